// Round 16
// baseline (53.711 us; speedup 1.0000x reference)
//
#include <hip/hip_runtime.h>
#include <cmath>

#define BB 64
#define KK 100
#define QQ 100
#define CC 82
#define AA 118
#define KP1 101
#define AM1 117
#define ROWF (KK * KP1)          // 10100 floats per (b,a) row
#define NROWS (BB * AM1)         // 7488 rows
#define PB 64                    // prep blocks (first in grid)
#define Z2 448                   // rows zeroed+fixed in dispatch 2 (tail)
#define Z1 (NROWS - Z2)          // 7040 rows zeroed in dispatch 1
#define ZCHUNK4 2525             // float4 per row
#define ECAP 16                  // max entries read opportunistically

typedef float vf4 __attribute__((ext_vector_type(4)));
typedef unsigned long long u64;

#define MAGICC 0x5EA1C0DEULL     // count-word magic (high 32 bits)
#define MAGICE 0x5AULL           // entry magic (high 8 bits)

// Dispatch 1.
// blocks [0,PB): per-batch prep -> small outputs + plain workspace arrays +
//   magic-tagged atomic publish words (per-word self-validating, no fences).
// blocks [PB, PB+Z1): zero one row; opportunistically read the published
//   list (reads issued before the zero loop, latency hidden); if valid ->
//   self-fix own row after the block barrier (flag=0) else flag=1.
__global__ __launch_bounds__(512) void fused_prep_zero(
    const float* __restrict__ logits,   // B,K,C
    const float* __restrict__ boxes_in, // B,K,4
    const float* __restrict__ actions,  // B,Q,A
    const float* __restrict__ hidx,     // B,Q,K
    const float* __restrict__ oidx,     // B,Q,K
    const int*   __restrict__ tsizes,   // B,2
    float* __restrict__ out_scores,     // B,K
    float* __restrict__ out_labels,     // B,K
    float* __restrict__ out_boxes,      // B,K,4
    float* __restrict__ out_pair,       // B,117,100,101
    u64*   __restrict__ pub,            // B*(QQ+1) atomic publish words
    int*   __restrict__ wsf,            // B,Q per-query flat segment id
    float* __restrict__ wsc,            // B,Q per-query coefficient
    int*   __restrict__ wsl,            // B,Q compacted matched-q list
    int*   __restrict__ wsn,            // B   matched count
    int*   __restrict__ flags)          // Z1 rows: 1=needs cleanup
{
    int blk = blockIdx.x;
    int tid = threadIdx.x;

    if (blk >= PB) {
        // ---------------- zero block: one row ----------------
        int r = blk - PB;
        int b = r / AM1;
        int a = r - b * AM1;
        u64* pubb = pub + (size_t)b * (QQ + 1);

        __shared__ u64 sh_cw, sh_e[ECAP];
        __shared__ int sh_bad;
        __shared__ int cp_f[ECAP], cp_q[ECAP];
        __shared__ float cp_c[ECAP];

        u64 cw = 0, ent = 0;
        if (tid == 0) { cw = atomicAdd(pubb, 0ULL); sh_bad = 0; }
        else if (tid <= ECAP) ent = atomicAdd(pubb + tid, 0ULL);

        vf4* dst = ((vf4*)out_pair) + (size_t)r * ZCHUNK4;
        const vf4 z = {0.f, 0.f, 0.f, 0.f};
        for (int i = tid; i < ZCHUNK4; i += 512) dst[i] = z;

        if (tid == 0) sh_cw = cw;
        else if (tid <= ECAP) sh_e[tid - 1] = ent;
        __syncthreads();   // zero stores drained; LDS stashes visible

        u64 c0 = sh_cw;
        bool ready = ((c0 >> 32) == MAGICC);
        int n = ready ? (int)(c0 & 0xFFFFFFFFULL) : 0;
        if (n > ECAP) ready = false;
        if (ready && tid < n && ((sh_e[tid] >> 56) != MAGICE)) sh_bad = 1;
        __syncthreads();

        bool fix = ready && !sh_bad;
        if (tid == 0) flags[r] = fix ? 0 : 1;
        if (!fix || n == 0) return;

        if (tid < n) {
            u64 e = sh_e[tid];
            cp_q[tid] = (int)(e & 0x3FF);
            cp_f[tid] = (int)((e >> 10) & 0x3FFF);
            cp_c[tid] = __uint_as_float((unsigned)(e >> 24));
        }
        __syncthreads();

        if (tid < n) {
            int j = tid, fj = cp_f[j];
            bool first = true;
            for (int i = 0; i < j; ++i)
                if (cp_f[i] == fj) { first = false; break; }
            if (first) {
                float val = 0.f;
                for (int i = j; i < n; ++i) {
                    if (cp_f[i] == fj) {
                        float x = actions[((size_t)b * QQ + cp_q[i]) * AA + a];
                        val += cp_c[i] / (1.f + expf(-x));
                    }
                }
                ((float*)dst)[fj] = val;
            }
        }
        return;
    }

    // ---------------- prep block: batch b ----------------
    int b = blk;
    __shared__ int   sh_h[QQ], sh_o[QQ];
    __shared__ float sh_ms[QQ], sh_labf[KK];
    __shared__ int   sh_spos[KK];
    __shared__ float sh_c[QQ];
    __shared__ int   sh_wcnt[2];
    __shared__ int   cpf[QQ], cpq[QQ];
    __shared__ float cpc[QQ];

    if (tid < KK) {
        const float2* l2 = (const float2*)(logits + ((size_t)b * KK + tid) * CC);
        float m = -INFINITY, best = -INFINITY; int bi = 0;
        #pragma unroll
        for (int i = 0; i < CC / 2; ++i) {
            float2 p = l2[i];
            m = fmaxf(m, fmaxf(p.x, p.y));
            if (p.x > best) { best = p.x; bi = 2 * i; }
            if (2 * i + 1 < CC - 1 && p.y > best) { best = p.y; bi = 2 * i + 1; }
        }
        float denom = 0.f;
        #pragma unroll
        for (int i = 0; i < CC / 2; ++i) {
            float2 p = l2[i];
            denom += expf(p.x - m) + expf(p.y - m);
        }
        float score = expf(best - m) / denom;
        sh_labf[tid] = (float)bi;
        sh_spos[tid] = (score > 0.0f) ? 1 : 0;
        out_scores[b * KK + tid] = score;
        out_labels[b * KK + tid] = (float)bi;

        const float4 bx = *(const float4*)(boxes_in + ((size_t)b * KK + tid) * 4);
        float ihh = (float)tsizes[b * 2 + 0];
        float iww = (float)tsizes[b * 2 + 1];
        float4 ob;
        ob.x = (bx.x - 0.5f * bx.z) * iww;
        ob.y = (bx.y - 0.5f * bx.w) * ihh;
        ob.z = (bx.x + 0.5f * bx.z) * iww;
        ob.w = (bx.y + 0.5f * bx.w) * ihh;
        *(float4*)(out_boxes + ((size_t)b * KK + tid) * 4) = ob;
    } else if (tid >= 128 && tid < 128 + QQ) {
        int q = tid - 128;  // argmax hidx (first occurrence, strict >)
        const float4* rp = (const float4*)(hidx + ((size_t)b * QQ + q) * KK);
        float best = -INFINITY; int bi = 0;
        #pragma unroll
        for (int i = 0; i < KK / 4; ++i) {
            float4 rr = rp[i];
            if (rr.x > best) { best = rr.x; bi = 4 * i; }
            if (rr.y > best) { best = rr.y; bi = 4 * i + 1; }
            if (rr.z > best) { best = rr.z; bi = 4 * i + 2; }
            if (rr.w > best) { best = rr.w; bi = 4 * i + 3; }
        }
        sh_h[q] = bi;
    } else if (tid >= 256 && tid < 256 + QQ) {
        int q = tid - 256;  // argmax oidx
        const float4* rp = (const float4*)(oidx + ((size_t)b * QQ + q) * KK);
        float best = -INFINITY; int bi = 0;
        #pragma unroll
        for (int i = 0; i < KK / 4; ++i) {
            float4 rr = rp[i];
            if (rr.x > best) { best = rr.x; bi = 4 * i; }
            if (rr.y > best) { best = rr.y; bi = 4 * i + 1; }
            if (rr.z > best) { best = rr.z; bi = 4 * i + 2; }
            if (rr.w > best) { best = rr.w; bi = 4 * i + 3; }
        }
        sh_o[q] = bi;
    } else if (tid >= 384 && tid < 384 + QQ) {
        int q = tid - 384;  // ms = 1 - sigmoid(last action)
        float x = actions[((size_t)b * QQ + q) * AA + (AA - 1)];
        sh_ms[q] = 1.f - 1.f / (1.f + expf(-x));
    }
    __syncthreads();

    if (tid < QQ) {
        int hh = sh_h[tid], oo = sh_o[tid];
        int f = hh * KP1 + oo;
        float myms = sh_ms[tid];
        bool winf = true;
        for (int q = 0; q < QQ; ++q) {
            if (sh_h[q] * KP1 + sh_o[q] == f) {
                float m2 = sh_ms[q];
                if (m2 > myms || (m2 == myms && q < tid)) { winf = false; break; }
            }
        }
        float hm = (sh_labf[hh] == 1.0f && sh_spos[hh]) ? 1.f : 0.f;
        float om = sh_spos[oo] ? 1.f : 0.f;
        float c = myms * (winf ? 2.f : 1.f) * hm * om;
        sh_c[tid] = c;
        wsf[b * QQ + tid] = f;
        wsc[b * QQ + tid] = c;
    }
    __syncthreads();

    if (tid < 128) {
        bool flag = (tid < QQ) && (sh_c[tid] != 0.f);
        unsigned long long bal = __ballot(flag);
        if ((tid & 63) == 0) sh_wcnt[tid >> 6] = __popcll(bal);
    }
    __syncthreads();
    if (tid < 128) {
        bool flag = (tid < QQ) && (sh_c[tid] != 0.f);
        unsigned long long bal = __ballot(flag);
        int base = (tid >> 6) ? sh_wcnt[0] : 0;
        if (flag) {
            int pos = base + __popcll(bal & ((1ull << (tid & 63)) - 1ull));
            wsl[b * QQ + pos] = tid;
            cpf[pos] = sh_h[tid] * KP1 + sh_o[tid];
            cpq[pos] = tid;
            cpc[pos] = sh_c[tid];
        }
        if (tid == 0) wsn[b] = sh_wcnt[0] + sh_wcnt[1];
    }
    __syncthreads();

    // publish magic-tagged entries + count (per-word self-validating).
    int n = sh_wcnt[0] + sh_wcnt[1];
    u64* pubb = pub + (size_t)b * (QQ + 1);
    if (tid < n) {
        u64 e = (MAGICE << 56)
              | ((u64)__float_as_uint(cpc[tid]) << 24)
              | ((u64)cpf[tid] << 10)
              | (u64)cpq[tid];
        atomicExch(pubb + 1 + tid, e);
    }
    if (tid == 0) atomicExch(pubb, (MAGICC << 32) | (u64)n);
}

// Dispatch 2.
// blocks [0,Z2): zero row (Z1+bid) then self-fix it (list guaranteed visible
//   across the dispatch boundary; full n via plain workspace arrays).
// blocks [Z2, Z2+BB): per-batch cleanup of flagged rows (<Z1) — this work
//   overlaps the Z2 blocks' streaming instead of trailing everything.
// All three value paths sum entries in ascending compacted order ->
// bit-identical output regardless of which path writes a cell.
__global__ __launch_bounds__(512) void tail_kernel(
    const float* __restrict__ actions, // B,Q,A
    const int*   __restrict__ wsf,
    const float* __restrict__ wsc,
    const int*   __restrict__ wsl,
    const int*   __restrict__ wsn,
    const int*   __restrict__ flags,
    float* __restrict__ out_pair)      // B,117,100,101
{
    int bid = blockIdx.x;
    int tid = threadIdx.x;

    if (bid < Z2) {
        int r = Z1 + bid;
        int b = r / AM1;
        int a = r - b * AM1;
        float* row = out_pair + (size_t)r * ROWF;
        vf4* dst = (vf4*)row;
        const vf4 z = {0.f, 0.f, 0.f, 0.f};
        for (int i = tid; i < ZCHUNK4; i += 512) dst[i] = z;
        __syncthreads();                // drain own zero stores

        int n = wsn[b];
        if (tid < n) {
            int qj = wsl[b * QQ + tid];
            int fj = wsf[b * QQ + qj];
            bool first = true;
            for (int i = 0; i < tid; ++i) {
                int qi = wsl[b * QQ + i];
                if (wsf[b * QQ + qi] == fj) { first = false; break; }
            }
            if (first) {
                float val = 0.f;
                for (int i = tid; i < n; ++i) {
                    int qi = wsl[b * QQ + i];
                    if (wsf[b * QQ + qi] == fj) {
                        float x = actions[((size_t)b * QQ + qi) * AA + a];
                        val += wsc[b * QQ + qi] / (1.f + expf(-x));
                    }
                }
                row[fj] = val;
            }
        }
        return;
    }

    // cleanup block for batch b: flagged rows (<Z1) only
    int b = bid - Z2;
    int n = wsn[b];
    int total = AM1 * n;
    for (int t = tid; t < total; t += 512) {
        int a = t / n;
        int j = t - a * n;
        int r = b * AM1 + a;
        if (r >= Z1 || !flags[r]) continue;
        int qj = wsl[b * QQ + j];
        int fj = wsf[b * QQ + qj];
        bool first = true;
        for (int i = 0; i < j; ++i) {
            int qi = wsl[b * QQ + i];
            if (wsf[b * QQ + qi] == fj) { first = false; break; }
        }
        if (first) {
            float val = 0.f;
            for (int i = j; i < n; ++i) {
                int qi = wsl[b * QQ + i];
                if (wsf[b * QQ + qi] == fj) {
                    float x = actions[((size_t)b * QQ + qi) * AA + a];
                    val += wsc[b * QQ + qi] / (1.f + expf(-x));
                }
            }
            out_pair[(size_t)r * ROWF + fj] = val;
        }
    }
}

extern "C" void kernel_launch(void* const* d_in, const int* in_sizes, int n_in,
                              void* d_out, int out_size, void* d_ws, size_t ws_size,
                              hipStream_t stream) {
    const float* pred_logits  = (const float*)d_in[0];
    const float* pred_boxes   = (const float*)d_in[1];
    const float* pred_actions = (const float*)d_in[2];
    const float* pred_hidx    = (const float*)d_in[3];
    const float* pred_oidx    = (const float*)d_in[4];
    const int*   target_sizes = (const int*)d_in[5];

    float* out = (float*)d_out;
    float* out_scores = out;                // B*K
    float* out_labels = out + BB * KK;      // B*K
    float* out_boxes  = out + 2 * BB * KK;  // B*K*4
    float* out_pair   = out + 6 * BB * KK;  // B*117*100*101

    u64*   pub = (u64*)d_ws;                     // B*(QQ+1) u64 (8B aligned)
    int*   wsf = (int*)(pub + BB * (QQ + 1));    // B*Q
    float* wsc = (float*)(wsf + BB * QQ);        // B*Q
    int*   wsl = (int*)(wsc + BB * QQ);          // B*Q
    int*   wsn = wsl + BB * QQ;                  // B
    int*   flags = wsn + BB;                     // Z1 rows

    fused_prep_zero<<<PB + Z1, 512, 0, stream>>>(
        pred_logits, pred_boxes, pred_actions, pred_hidx, pred_oidx,
        target_sizes, out_scores, out_labels, out_boxes, out_pair,
        pub, wsf, wsc, wsl, wsn, flags);

    tail_kernel<<<Z2 + BB, 512, 0, stream>>>(
        pred_actions, wsf, wsc, wsl, wsn, flags, out_pair);
}

// Round 17
// 51.547 us; speedup vs baseline: 1.0420x; 1.0420x over previous
//
#include <hip/hip_runtime.h>
#include <cmath>

#define BB 64
#define KK 100
#define QQ 100
#define CC 82
#define AA 118
#define KP1 101
#define AM1 117
#define ROWF (KK * KP1)          // 10100 floats per (b,a) row
#define NROWS (BB * AM1)         // 7488 rows
#define PB 64                    // prep blocks (first in grid)
#define ZCHUNK4 2525             // float4 per row
#define ECAP 16                  // max entries read opportunistically

typedef float vf4 __attribute__((ext_vector_type(4)));
typedef unsigned long long u64;

#define MAGICC 0x5EA1C0DEULL     // count-word magic (high 32 bits)
#define MAGICE 0x5AULL           // entry magic (high 8 bits)

// Dispatch 1.
// blocks [0,PB): per-batch prep -> small outputs + plain workspace arrays +
//   magic-tagged publish words via coherent (agent-scope) relaxed stores.
// blocks [PB, PB+NROWS): zero one row; opportunistically read the published
//   list via coherent relaxed LOADS (no RMW serialization; issued before the
//   zero loop so latency hides under the stores); if valid -> self-fix own
//   row after the block barrier (flag=0) else flag=1 for cleanup.
__global__ __launch_bounds__(512) void fused_prep_zero(
    const float* __restrict__ logits,   // B,K,C
    const float* __restrict__ boxes_in, // B,K,4
    const float* __restrict__ actions,  // B,Q,A
    const float* __restrict__ hidx,     // B,Q,K
    const float* __restrict__ oidx,     // B,Q,K
    const int*   __restrict__ tsizes,   // B,2
    float* __restrict__ out_scores,     // B,K
    float* __restrict__ out_labels,     // B,K
    float* __restrict__ out_boxes,      // B,K,4
    float* __restrict__ out_pair,       // B,117,100,101
    u64*   __restrict__ pub,            // B*(QQ+1) publish words
    int*   __restrict__ wsf,            // B,Q per-query flat segment id
    float* __restrict__ wsc,            // B,Q per-query coefficient
    int*   __restrict__ wsl,            // B,Q compacted matched-q list
    int*   __restrict__ wsn,            // B   matched count
    int*   __restrict__ flags)          // NROWS 1=needs cleanup
{
    int blk = blockIdx.x;
    int tid = threadIdx.x;

    if (blk >= PB) {
        // ---------------- zero block: one row ----------------
        int r = blk - PB;
        int b = r / AM1;
        int a = r - b * AM1;
        u64* pubb = pub + (size_t)b * (QQ + 1);

        __shared__ u64 sh_cw, sh_e[ECAP];
        __shared__ int sh_bad;
        __shared__ int cp_f[ECAP], cp_q[ECAP];
        __shared__ float cp_c[ECAP];

        u64 cw = 0, ent = 0;
        if (tid == 0) {
            cw = __hip_atomic_load(pubb, __ATOMIC_RELAXED,
                                   __HIP_MEMORY_SCOPE_AGENT);
            sh_bad = 0;
        } else if (tid <= ECAP) {
            ent = __hip_atomic_load(pubb + tid, __ATOMIC_RELAXED,
                                    __HIP_MEMORY_SCOPE_AGENT);
        }

        vf4* dst = ((vf4*)out_pair) + (size_t)r * ZCHUNK4;
        const vf4 z = {0.f, 0.f, 0.f, 0.f};
        for (int i = tid; i < ZCHUNK4; i += 512) dst[i] = z;

        if (tid == 0) sh_cw = cw;
        else if (tid <= ECAP) sh_e[tid - 1] = ent;
        __syncthreads();   // zero stores drained; LDS stashes visible

        u64 c0 = sh_cw;
        bool ready = ((c0 >> 32) == MAGICC);
        int n = ready ? (int)(c0 & 0xFFFFFFFFULL) : 0;
        if (n > ECAP) ready = false;
        if (ready && tid < n && ((sh_e[tid] >> 56) != MAGICE)) sh_bad = 1;
        __syncthreads();

        bool fix = ready && !sh_bad;
        if (tid == 0) flags[r] = fix ? 0 : 1;
        if (!fix || n == 0) return;

        if (tid < n) {
            u64 e = sh_e[tid];
            cp_q[tid] = (int)(e & 0x3FF);
            cp_f[tid] = (int)((e >> 10) & 0x3FFF);
            cp_c[tid] = __uint_as_float((unsigned)(e >> 24));
        }
        __syncthreads();

        if (tid < n) {
            int j = tid, fj = cp_f[j];
            bool first = true;
            for (int i = 0; i < j; ++i)
                if (cp_f[i] == fj) { first = false; break; }
            if (first) {
                float val = 0.f;
                for (int i = j; i < n; ++i) {
                    if (cp_f[i] == fj) {
                        float x = actions[((size_t)b * QQ + cp_q[i]) * AA + a];
                        val += cp_c[i] / (1.f + expf(-x));
                    }
                }
                ((float*)dst)[fj] = val;
            }
        }
        return;
    }

    // ---------------- prep block: batch b ----------------
    int b = blk;
    __shared__ int   sh_h[QQ], sh_o[QQ];
    __shared__ float sh_ms[QQ], sh_labf[KK];
    __shared__ int   sh_spos[KK];
    __shared__ float sh_c[QQ];
    __shared__ int   sh_wcnt[2];
    __shared__ int   cpf[QQ], cpq[QQ];
    __shared__ float cpc[QQ];

    if (tid < KK) {
        const float2* l2 = (const float2*)(logits + ((size_t)b * KK + tid) * CC);
        float m = -INFINITY, best = -INFINITY; int bi = 0;
        #pragma unroll
        for (int i = 0; i < CC / 2; ++i) {
            float2 p = l2[i];
            m = fmaxf(m, fmaxf(p.x, p.y));
            if (p.x > best) { best = p.x; bi = 2 * i; }
            if (2 * i + 1 < CC - 1 && p.y > best) { best = p.y; bi = 2 * i + 1; }
        }
        float denom = 0.f;
        #pragma unroll
        for (int i = 0; i < CC / 2; ++i) {
            float2 p = l2[i];
            denom += expf(p.x - m) + expf(p.y - m);
        }
        float score = expf(best - m) / denom;
        sh_labf[tid] = (float)bi;
        sh_spos[tid] = (score > 0.0f) ? 1 : 0;
        out_scores[b * KK + tid] = score;
        out_labels[b * KK + tid] = (float)bi;

        const float4 bx = *(const float4*)(boxes_in + ((size_t)b * KK + tid) * 4);
        float ihh = (float)tsizes[b * 2 + 0];
        float iww = (float)tsizes[b * 2 + 1];
        float4 ob;
        ob.x = (bx.x - 0.5f * bx.z) * iww;
        ob.y = (bx.y - 0.5f * bx.w) * ihh;
        ob.z = (bx.x + 0.5f * bx.z) * iww;
        ob.w = (bx.y + 0.5f * bx.w) * ihh;
        *(float4*)(out_boxes + ((size_t)b * KK + tid) * 4) = ob;
    } else if (tid >= 128 && tid < 128 + QQ) {
        int q = tid - 128;  // argmax hidx (first occurrence, strict >)
        const float4* rp = (const float4*)(hidx + ((size_t)b * QQ + q) * KK);
        float best = -INFINITY; int bi = 0;
        #pragma unroll
        for (int i = 0; i < KK / 4; ++i) {
            float4 rr = rp[i];
            if (rr.x > best) { best = rr.x; bi = 4 * i; }
            if (rr.y > best) { best = rr.y; bi = 4 * i + 1; }
            if (rr.z > best) { best = rr.z; bi = 4 * i + 2; }
            if (rr.w > best) { best = rr.w; bi = 4 * i + 3; }
        }
        sh_h[q] = bi;
    } else if (tid >= 256 && tid < 256 + QQ) {
        int q = tid - 256;  // argmax oidx
        const float4* rp = (const float4*)(oidx + ((size_t)b * QQ + q) * KK);
        float best = -INFINITY; int bi = 0;
        #pragma unroll
        for (int i = 0; i < KK / 4; ++i) {
            float4 rr = rp[i];
            if (rr.x > best) { best = rr.x; bi = 4 * i; }
            if (rr.y > best) { best = rr.y; bi = 4 * i + 1; }
            if (rr.z > best) { best = rr.z; bi = 4 * i + 2; }
            if (rr.w > best) { best = rr.w; bi = 4 * i + 3; }
        }
        sh_o[q] = bi;
    } else if (tid >= 384 && tid < 384 + QQ) {
        int q = tid - 384;  // ms = 1 - sigmoid(last action)
        float x = actions[((size_t)b * QQ + q) * AA + (AA - 1)];
        sh_ms[q] = 1.f - 1.f / (1.f + expf(-x));
    }
    __syncthreads();

    if (tid < QQ) {
        int hh = sh_h[tid], oo = sh_o[tid];
        int f = hh * KP1 + oo;
        float myms = sh_ms[tid];
        bool winf = true;
        for (int q = 0; q < QQ; ++q) {
            if (sh_h[q] * KP1 + sh_o[q] == f) {
                float m2 = sh_ms[q];
                if (m2 > myms || (m2 == myms && q < tid)) { winf = false; break; }
            }
        }
        float hm = (sh_labf[hh] == 1.0f && sh_spos[hh]) ? 1.f : 0.f;
        float om = sh_spos[oo] ? 1.f : 0.f;
        float c = myms * (winf ? 2.f : 1.f) * hm * om;
        sh_c[tid] = c;
        wsf[b * QQ + tid] = f;
        wsc[b * QQ + tid] = c;
    }
    __syncthreads();

    if (tid < 128) {
        bool flag = (tid < QQ) && (sh_c[tid] != 0.f);
        unsigned long long bal = __ballot(flag);
        if ((tid & 63) == 0) sh_wcnt[tid >> 6] = __popcll(bal);
    }
    __syncthreads();
    if (tid < 128) {
        bool flag = (tid < QQ) && (sh_c[tid] != 0.f);
        unsigned long long bal = __ballot(flag);
        int base = (tid >> 6) ? sh_wcnt[0] : 0;
        if (flag) {
            int pos = base + __popcll(bal & ((1ull << (tid & 63)) - 1ull));
            wsl[b * QQ + pos] = tid;
            cpf[pos] = sh_h[tid] * KP1 + sh_o[tid];
            cpq[pos] = tid;
            cpc[pos] = sh_c[tid];
        }
        if (tid == 0) wsn[b] = sh_wcnt[0] + sh_wcnt[1];
    }
    __syncthreads();

    // publish magic-tagged entries + count via coherent relaxed stores
    // (per-word self-validating; poison 0xAA.. fails both magic checks).
    int n = sh_wcnt[0] + sh_wcnt[1];
    u64* pubb = pub + (size_t)b * (QQ + 1);
    if (tid < n) {
        u64 e = (MAGICE << 56)
              | ((u64)__float_as_uint(cpc[tid]) << 24)
              | ((u64)cpf[tid] << 10)
              | (u64)cpq[tid];
        __hip_atomic_store(pubb + 1 + tid, e, __ATOMIC_RELAXED,
                           __HIP_MEMORY_SCOPE_AGENT);
    }
    if (tid == 0)
        __hip_atomic_store(pubb, (MAGICC << 32) | (u64)n, __ATOMIC_RELAXED,
                           __HIP_MEMORY_SCOPE_AGENT);
}

// Dispatch 2: cleanup. 64 blocks; block b writes value cells only for its
// flagged rows (zeroed in dispatch 1; boundary gives visibility; flagged
// rows were NOT touched by self-fix -> plain stores, no contention).
// Summation order identical to the self-fix path -> bit-identical output.
__global__ __launch_bounds__(512) void cleanup_kernel(
    const float* __restrict__ actions, // B,Q,A
    const int*   __restrict__ wsf,
    const float* __restrict__ wsc,
    const int*   __restrict__ wsl,
    const int*   __restrict__ wsn,
    const int*   __restrict__ flags,
    float* __restrict__ out_pair)      // B,117,100,101
{
    int b = blockIdx.x;
    int tid = threadIdx.x;
    int n = wsn[b];
    int total = AM1 * n;
    for (int t = tid; t < total; t += 512) {
        int a = t / n;
        int j = t - a * n;
        int r = b * AM1 + a;
        if (!flags[r]) continue;
        int qj = wsl[b * QQ + j];
        int fj = wsf[b * QQ + qj];
        bool first = true;
        for (int i = 0; i < j; ++i) {
            int qi = wsl[b * QQ + i];
            if (wsf[b * QQ + qi] == fj) { first = false; break; }
        }
        if (first) {
            float val = 0.f;
            for (int i = j; i < n; ++i) {
                int qi = wsl[b * QQ + i];
                if (wsf[b * QQ + qi] == fj) {
                    float x = actions[((size_t)b * QQ + qi) * AA + a];
                    val += wsc[b * QQ + qi] / (1.f + expf(-x));
                }
            }
            out_pair[(size_t)r * ROWF + fj] = val;
        }
    }
}

extern "C" void kernel_launch(void* const* d_in, const int* in_sizes, int n_in,
                              void* d_out, int out_size, void* d_ws, size_t ws_size,
                              hipStream_t stream) {
    const float* pred_logits  = (const float*)d_in[0];
    const float* pred_boxes   = (const float*)d_in[1];
    const float* pred_actions = (const float*)d_in[2];
    const float* pred_hidx    = (const float*)d_in[3];
    const float* pred_oidx    = (const float*)d_in[4];
    const int*   target_sizes = (const int*)d_in[5];

    float* out = (float*)d_out;
    float* out_scores = out;                // B*K
    float* out_labels = out + BB * KK;      // B*K
    float* out_boxes  = out + 2 * BB * KK;  // B*K*4
    float* out_pair   = out + 6 * BB * KK;  // B*117*100*101

    u64*   pub = (u64*)d_ws;                     // B*(QQ+1) u64 (8B aligned)
    int*   wsf = (int*)(pub + BB * (QQ + 1));    // B*Q
    float* wsc = (float*)(wsf + BB * QQ);        // B*Q
    int*   wsl = (int*)(wsc + BB * QQ);          // B*Q
    int*   wsn = wsl + BB * QQ;                  // B
    int*   flags = wsn + BB;                     // NROWS

    fused_prep_zero<<<PB + NROWS, 512, 0, stream>>>(
        pred_logits, pred_boxes, pred_actions, pred_hidx, pred_oidx,
        target_sizes, out_scores, out_labels, out_boxes, out_pair,
        pub, wsf, wsc, wsl, wsn, flags);

    cleanup_kernel<<<BB, 512, 0, stream>>>(
        pred_actions, wsf, wsc, wsl, wsn, flags, out_pair);
}